// Round 7
// baseline (202.599 us; speedup 1.0000x reference)
//
#include <hip/hip_runtime.h>

#define B_  32
#define C_  128
#define CS  64
#define H_  64
#define W_  64
#define HW  (H_*W_)

typedef __attribute__((ext_vector_type(8))) short bf16x8_t;
typedef __attribute__((ext_vector_type(4))) float f32x4_t;
typedef unsigned short u16;
typedef unsigned int   u32;

__device__ __forceinline__ float silu_f(float v) { return v / (1.f + __expf(-v)); }

__device__ __forceinline__ u16 f2bf(float f) {
    u32 u = __float_as_uint(f);
    u = (u + 0x7FFFu + ((u >> 16) & 1u)) >> 16;   // RNE
    return (u16)u;
}
__device__ __forceinline__ float bf2f(u16 u) {
    return __uint_as_float(((u32)u) << 16);
}
__device__ __forceinline__ u32 pack2(float a, float b) {
    return (u32)f2bf(a) | ((u32)f2bf(b) << 16);
}

__device__ __forceinline__ void get_coeffs(const float* __restrict__ wts,
                                           const int* __restrict__ idxs, int b,
                                           float& c0, float& c1, float& c2, float& cid) {
    int   i0 = idxs[b*2+0], i1 = idxs[b*2+1];
    float w0 = wts[b*2+0],  w1 = wts[b*2+1];
    c0  = (i0==0?w0:0.f)   + (i1==0?w1:0.f);
    c1  = (i0==1?w0:0.f)   + (i1==1?w1:0.f);
    c2  = (i0==2?w0:0.f)   + (i1==2?w1:0.f);
    cid = (i0==3?0.1f:0.f) + (i1==3?0.1f:0.f);
}

// XCD-pinning decode: hardware assigns wgid%8 -> XCD (round-robin).
// All blocks of batch b land on XCD b%8; 4 batches per XCD.
__device__ __forceinline__ void xcd_decode(int bid, int& b, int& widx) {
    int xcd = bid & 7;
    int slot = bid >> 3;
    b = xcd + ((slot & 3) << 3) + ((slot & 3) >> 2);   // b = xcd + 8*sub
    b = xcd + ((slot & 3) << 3);
    widx = slot >> 2;
}

// ---- weight prep: MFMA-fragment-ordered bf16 weights --------------------------
// Wt0f: e0  [tap9][kc2][cog8][lane64][8]   A[row=co=cog*16+(l&15)][k=kc*32+(l>>4)*8+j]
// Wt2f: e2a [tap9][kc4][cog4][lane64][8]
// Wt1f: e1pw[kc2][cog8][lane64][8]
__global__ __launch_bounds__(256) void k_prep(
    const float* __restrict__ e0w, const float* __restrict__ e2aw, const float* __restrict__ e1pw,
    u16* __restrict__ Wt0f, u16* __restrict__ Wt2f, u16* __restrict__ Wt1f)
{
    const int i0 = blockIdx.x*256 + threadIdx.x, stride = gridDim.x*256;
    for (int i = i0; i < 73728; i += stride) {
        int j = i&7, lane = (i>>3)&63, cog = (i>>9)&7, kc = (i>>12)&1, tap = i>>13;
        int co = cog*16 + (lane&15), ci = kc*32 + (lane>>4)*8 + j;
        Wt0f[i] = f2bf(e0w[(size_t)(co*64 + ci)*9 + tap]);
    }
    for (int i = i0; i < 73728; i += stride) {
        int j = i&7, lane = (i>>3)&63, cog = (i>>9)&3, kc = (i>>11)&3, tap = i>>13;
        int co = cog*16 + (lane&15), ci = kc*32 + (lane>>4)*8 + j;
        Wt2f[i] = f2bf(e2aw[(size_t)(co*128 + ci)*9 + tap]);
    }
    for (int i = i0; i < 8192; i += stride) {
        int j = i&7, lane = (i>>3)&63, cog = (i>>9)&7, kc = (i>>12)&1;
        int co = cog*16 + (lane&15), ci = kc*32 + (lane>>4)*8 + j;
        Wt1f[i] = f2bf(e1pw[(size_t)co*64 + ci]);
    }
}

// ---- NCHW fp32 -> padded NHWC bf16 [b][66][66][128], zero borders -------------
// grid: 2048 1-D, XCD-pinned: h = widx
__global__ __launch_bounds__(256) void k_to_nhwc(
    const float* __restrict__ x, const float* __restrict__ wts, const int* __restrict__ idxs,
    u16* __restrict__ xh)
{
    int b, h;
    xcd_decode(blockIdx.x, b, h);
    const int t = threadIdx.x;
    float c0, c1, c2, cid;
    get_coeffs(wts, idxs, b, c0, c1, c2, cid);
    if (c0 == 0.f && c2 == 0.f) return;
    const int chmax = (c2 != 0.f) ? 128 : 64;

    __shared__ float ld[128*66];
    for (int i = t; i < chmax*16; i += 256) {
        int ch = i >> 4, q = i & 15;
        float4 v = *(const float4*)(x + ((size_t)(b*C_+ch))*HW + h*64 + q*4);
        float* p = &ld[ch*66 + q*4];
        p[0] = v.x; p[1] = v.y; p[2] = v.z; p[3] = v.w;
    }
    __syncthreads();

    const int px = t >> 2, sub = t & 3;
    u16* rec = xh + ((size_t)(b*66 + h+1)*66 + (px+1))*C_;
    for (int c = sub; c < chmax/8; c += 4) {
        uint4 v;
        u32 w[4];
        #pragma unroll
        for (int k = 0; k < 4; ++k)
            w[k] = pack2(ld[(c*8 + 2*k)*66 + px], ld[(c*8 + 2*k + 1)*66 + px]);
        v.x = w[0]; v.y = w[1]; v.z = w[2]; v.w = w[3];
        *(uint4*)(rec + c*8) = v;
    }
    if (t < 32) {
        int col = (t >> 4) * 65, cg = t & 15;
        uint4 z; z.x = z.y = z.z = z.w = 0u;
        *(uint4*)(xh + ((size_t)(b*66 + h+1)*66 + col)*C_ + cg*8) = z;
    }
    if (h == 0 || h == 63) {
        int r = (h == 0) ? 0 : 65;
        uint4 z; z.x = z.y = z.z = z.w = 0u;
        for (int i = t; i < 66*16; i += 256) {
            int col = i >> 4, cg = i & 15;
            *(uint4*)(xh + ((size_t)(b*66 + r)*66 + col)*C_ + cg*8) = z;
        }
    }
}

// ---- per-wave conv tile: 64 couts x 64 px (one row), bf16 MFMA ---------------
// MODE 0: e0  (CIN=64,  COUT=128): out = cexp*silu(bn(conv)) + cid*x
// MODE 1: e2a (CIN=128, COUT=64) : g1 = silu(bn(conv)) bf16
template<int CIN, int COUT, int MODE>
__device__ __forceinline__ void conv_body(
    const u16* __restrict__ xh, const float* __restrict__ x,
    const u16* __restrict__ Wtf,
    const float* __restrict__ gg, const float* __restrict__ bbn,
    const float* __restrict__ mm, const float* __restrict__ vv,
    float* __restrict__ out, u16* __restrict__ g1,
    int b, int mtile, int row, int lane, float cexp, float cid)
{
    constexpr int KC = CIN/32, NIT = 9*KC;
    const int l15 = lane & 15, kg = lane >> 4;

    f32x4_t acc[4][4];
    #pragma unroll
    for (int cf = 0; cf < 4; ++cf)
        #pragma unroll
        for (int pf = 0; pf < 4; ++pf)
            acc[cf][pf] = (f32x4_t){0.f, 0.f, 0.f, 0.f};

    const u16* xb = xh + ((size_t)(b*66 + row)*66)*C_ + kg*8;
    const u16* wb = Wtf + (size_t)(mtile*4)*512 + (size_t)lane*8;

    bf16x8_t aA[4], bA[4], aB[4], bB[4];

    auto LD = [&](int it, bf16x8_t* af, bf16x8_t* bf) {
        const int tap = it / KC, kc = it % KC;
        const int dh = tap/3, dwp = tap%3;
        const u16* wt = wb + (size_t)((tap*KC + kc)*(COUT/16))*512;
        #pragma unroll
        for (int cf = 0; cf < 4; ++cf)
            af[cf] = *(const bf16x8_t*)(wt + (cf << 9));
        #pragma unroll
        for (int pf = 0; pf < 4; ++pf)
            bf[pf] = *(const bf16x8_t*)(xb + (size_t)(dh*66 + pf*16 + l15 + dwp)*C_ + kc*32);
    };

    LD(0, aA, bA);
    #pragma unroll
    for (int it = 0; it < NIT; ++it) {
        bf16x8_t* ac = (it & 1) ? aB : aA;
        bf16x8_t* bc = (it & 1) ? bB : bA;
        bf16x8_t* an = (it & 1) ? aA : aB;
        bf16x8_t* bn = (it & 1) ? bA : bB;
        if (it + 1 < NIT) LD(it + 1, an, bn);
        #pragma unroll
        for (int pf = 0; pf < 4; ++pf)
            #pragma unroll
            for (int cf = 0; cf < 4; ++cf)
                acc[cf][pf] = __builtin_amdgcn_mfma_f32_16x16x32_bf16(ac[cf], bc[pf], acc[cf][pf], 0, 0, 0);
    }

    // D: col=lane&15=pixel, row=(lane>>4)*4+reg=cout
    #pragma unroll
    for (int cf = 0; cf < 4; ++cf) {
        float sarr[4], tarr[4];
        #pragma unroll
        for (int r = 0; r < 4; ++r) {
            int co = mtile*64 + cf*16 + kg*4 + r;
            float s = gg[co] * rsqrtf(vv[co] + 1e-5f);
            sarr[r] = s; tarr[r] = bbn[co] - mm[co]*s;
        }
        #pragma unroll
        for (int pf = 0; pf < 4; ++pf) {
            int px = pf*16 + l15;
            size_t rowoff = (size_t)row*64 + px;
            #pragma unroll
            for (int r = 0; r < 4; ++r) {
                int co = mtile*64 + cf*16 + kg*4 + r;
                float v = silu_f(acc[cf][pf][r]*sarr[r] + tarr[r]);
                if (MODE == 0) {
                    size_t o = ((size_t)(b*C_+co))*HW + rowoff;
                    float idv = (cid != 0.f) ? cid*x[o] : 0.f;
                    out[o] = cexp*v + idv;
                } else {
                    g1[((size_t)(b*CS+co))*HW + rowoff] = f2bf(v);
                }
            }
        }
    }
}

// ---- merged conv kernel, 1 wave per block, XCD-pinned grid (6144 1-D) ---------
// widx in [0,128): e0 tile, mtile=widx>>6, row=widx&63  (c0==0 -> identity init)
// widx in [128,192): e2a tile, row=widx-128
__global__ __launch_bounds__(64, 3) void k_conv(
    const u16* __restrict__ xh, const float* __restrict__ x,
    const float* __restrict__ wts, const int* __restrict__ idxs,
    const u16* __restrict__ Wt0f, const u16* __restrict__ Wt2f,
    const float* __restrict__ e0g, const float* __restrict__ e0b,
    const float* __restrict__ e0m, const float* __restrict__ e0v,
    const float* __restrict__ e2ag, const float* __restrict__ e2ab,
    const float* __restrict__ e2am, const float* __restrict__ e2av,
    float* __restrict__ out, u16* __restrict__ g1)
{
    int b, bx;
    xcd_decode(blockIdx.x, b, bx);
    const int lane = threadIdx.x;
    float c0, c1, c2, cid;
    get_coeffs(wts, idxs, b, c0, c1, c2, cid);

    if (bx < 128) {
        const int mtile = bx >> 6, row = bx & 63;
        if (c0 == 0.f) {   // identity-only init of this row, couts mtile*64..+63
            #pragma unroll
            for (int k = 0; k < 16; ++k) {
                int ch = mtile*64 + k*4 + (lane >> 4);
                size_t o = ((size_t)(b*C_+ch))*HW + (size_t)row*64 + (lane & 15)*4;
                float4 ov;
                if (cid != 0.f) {
                    float4 xv = *(const float4*)(x + o);
                    ov.x = cid*xv.x; ov.y = cid*xv.y; ov.z = cid*xv.z; ov.w = cid*xv.w;
                } else { ov.x = ov.y = ov.z = ov.w = 0.f; }
                *(float4*)(out + o) = ov;
            }
            return;
        }
        conv_body<64, 128, 0>(xh, x, Wt0f, e0g, e0b, e0m, e0v, out, nullptr,
                              b, mtile, row, lane, c0, cid);
    } else {
        if (c2 == 0.f) return;
        const int row = bx - 128;
        conv_body<128, 64, 1>(xh, x, Wt2f, e2ag, e2ab, e2am, e2av, nullptr, g1,
                              b, 0, row, lane, c2, 0.f);
    }
}

// ---- fused e1: dw5x5(x_ir) in LDS -> pw1x1 MFMA -> BN/SiLU -> out += c1*e1 ----
// grid: 1024 1-D XCD-pinned, band = widx
__global__ __launch_bounds__(256) void k_e1(
    const float* __restrict__ x, const float* __restrict__ wts, const int* __restrict__ idxs,
    const float* __restrict__ dww, const u16* __restrict__ Wt1f,
    const float* __restrict__ gg, const float* __restrict__ bb,
    const float* __restrict__ mm, const float* __restrict__ vv,
    float* __restrict__ out)
{
    int b, band;
    xcd_decode(blockIdx.x, b, band);
    const int t = threadIdx.x;
    const int orow0 = band*2;

    float c0, c1, c2, cid;
    get_coeffs(wts, idxs, b, c0, c1, c2, cid);
    if (c1 == 0.f) return;

    __shared__ u16  lin[6*64*70];   // [row6][ch64][col70] cols -2..65 (+pad), bf16
    __shared__ u16  lout[128*72];   // [px128][ci72pad] bf16
    __shared__ float wl[64*26];

    for (int i = t; i < 64*25; i += 256) wl[(i/25)*26 + (i%25)] = dww[i];
    for (int i = t; i < 6*64*16; i += 256) {
        int q = i & 15, ch = (i >> 4) & 63, r = i >> 10;
        int hh = orow0 - 2 + r;
        u32 w0 = 0u, w1 = 0u;
        if (hh >= 0 && hh < H_) {
            float4 v = *(const float4*)(x + ((size_t)(b*C_ + CS + ch))*HW + hh*64 + q*4);
            w0 = pack2(v.x, v.y); w1 = pack2(v.z, v.w);
        }
        u32* dst = (u32*)&lin[(r*64 + ch)*70 + 2 + q*4];
        dst[0] = w0; dst[1] = w1;
    }
    for (int i = t; i < 6*64; i += 256) {
        int ch = i & 63, r = i >> 6;
        *(u32*)&lin[(r*64 + ch)*70]      = 0u;
        u32* e = (u32*)&lin[(r*64 + ch)*70 + 66];
        e[0] = 0u; e[1] = 0u;
    }
    __syncthreads();

    const int lane = t & 63, chl = lane & 15, cs = lane >> 4;
    const int wv = t >> 6, outrow = wv & 1, chhalf = wv >> 1;

    #pragma unroll
    for (int chi = 0; chi < 2; ++chi) {
        const int ch = chhalf*32 + chl + chi*16;
        const float* wch = &wl[ch*26];
        float accp[16];
        #pragma unroll
        for (int p = 0; p < 16; ++p) accp[p] = 0.f;
        #pragma unroll
        for (int kh = 0; kh < 5; ++kh) {
            const u16* src = &lin[((outrow + kh)*64 + ch)*70 + cs*16];
            float rb[20];
            #pragma unroll
            for (int k = 0; k < 10; ++k) {
                u32 u = *(const u32*)(src + 2*k);
                rb[2*k]   = __uint_as_float(u << 16);
                rb[2*k+1] = __uint_as_float(u & 0xFFFF0000u);
            }
            #pragma unroll
            for (int kw = 0; kw < 5; ++kw) {
                float wvv = wch[kh*5 + kw];
                #pragma unroll
                for (int p = 0; p < 16; ++p) accp[p] += rb[p+kw]*wvv;
            }
        }
        const int px0 = outrow*64 + cs*16;
        #pragma unroll
        for (int p = 0; p < 16; ++p) lout[(px0+p)*72 + ch] = f2bf(accp[p]);
    }
    __syncthreads();

    const int l15 = lane & 15, kg = lane >> 4;
    const int cw = wv >> 1, pwv = wv & 1;
    f32x4_t acc[4][4];
    #pragma unroll
    for (int cf = 0; cf < 4; ++cf)
        #pragma unroll
        for (int pf = 0; pf < 4; ++pf)
            acc[cf][pf] = (f32x4_t){0.f, 0.f, 0.f, 0.f};

    #pragma unroll
    for (int kc = 0; kc < 2; ++kc) {
        const u16* wt = Wt1f + (((size_t)(kc*8 + cw*4)) << 9) + lane*8;
        bf16x8_t af[4];
        #pragma unroll
        for (int cf = 0; cf < 4; ++cf) af[cf] = *(const bf16x8_t*)(wt + (cf << 9));
        const int k0 = kc*32 + kg*8;
        #pragma unroll
        for (int pf = 0; pf < 4; ++pf) {
            bf16x8_t bfr = *(const bf16x8_t*)&lout[(pwv*64 + pf*16 + l15)*72 + k0];
            #pragma unroll
            for (int cf = 0; cf < 4; ++cf)
                acc[cf][pf] = __builtin_amdgcn_mfma_f32_16x16x32_bf16(af[cf], bfr, acc[cf][pf], 0, 0, 0);
        }
    }

    #pragma unroll
    for (int cf = 0; cf < 4; ++cf) {
        float sarr[4], tarr[4];
        #pragma unroll
        for (int r = 0; r < 4; ++r) {
            int co = cw*64 + cf*16 + kg*4 + r;
            float s = gg[co] * rsqrtf(vv[co] + 1e-5f);
            sarr[r] = s; tarr[r] = bb[co] - mm[co]*s;
        }
        #pragma unroll
        for (int pf = 0; pf < 4; ++pf) {
            int px = pwv*64 + pf*16 + l15;
            size_t rowoff = (size_t)(orow0 + (px>>6))*64 + (px&63);
            #pragma unroll
            for (int r = 0; r < 4; ++r) {
                int co = cw*64 + cf*16 + kg*4 + r;
                float v = silu_f(acc[cf][pf][r]*sarr[r] + tarr[r]);
                out[((size_t)(b*C_+co))*HW + rowoff] += c1*v;
            }
        }
    }
}

// ---- e2b: out[:, :64] += c2*g1 ; out[:, 64:] += c2*silu(bn(dw5x5(g1))) --------
// grid: 1024 1-D XCD-pinned, band = widx
__global__ __launch_bounds__(256) void k_e2b(
    const u16* __restrict__ g1, const float* __restrict__ wts, const int* __restrict__ idxs,
    const float* __restrict__ dww, const float* __restrict__ gg, const float* __restrict__ bb,
    const float* __restrict__ mm, const float* __restrict__ vv, float* __restrict__ out)
{
    int b, band;
    xcd_decode(blockIdx.x, b, band);
    const int t = threadIdx.x;
    const int orow0 = band*2;

    float c0, c1, c2, cid;
    get_coeffs(wts, idxs, b, c0, c1, c2, cid);
    if (c2 == 0.f) return;

    __shared__ u16  lin[6*64*70];
    __shared__ float wl[64*26];

    for (int i = t; i < 64*25; i += 256) wl[(i/25)*26 + (i%25)] = dww[i];
    for (int i = t; i < 6*64*16; i += 256) {
        int q = i & 15, ch = (i >> 4) & 63, r = i >> 10;
        int hh = orow0 - 2 + r;
        u32 w0 = 0u, w1 = 0u;
        if (hh >= 0 && hh < H_) {
            const u32* src = (const u32*)(g1 + ((size_t)(b*CS+ch))*HW + hh*64 + q*4);
            w0 = src[0]; w1 = src[1];
        }
        u32* dst = (u32*)&lin[(r*64 + ch)*70 + 2 + q*4];
        dst[0] = w0; dst[1] = w1;
    }
    for (int i = t; i < 6*64; i += 256) {
        int ch = i & 63, r = i >> 6;
        *(u32*)&lin[(r*64 + ch)*70] = 0u;
        u32* e = (u32*)&lin[(r*64 + ch)*70 + 66];
        e[0] = 0u; e[1] = 0u;
    }
    __syncthreads();

    // out[:, :64] += c2*g1 for the 2 center rows (lin rows 2,3)
    for (int i = t; i < 2*64*16; i += 256) {
        int q = i & 15, ch = (i >> 4) & 63, r = i >> 10;
        const u16* src = &lin[((r+2)*64 + ch)*70 + 2 + q*4];
        float* op = out + ((size_t)(b*C_+ch))*HW + (size_t)(orow0+r)*64 + q*4;
        float4 ov = *(float4*)op;
        ov.x += c2*bf2f(src[0]); ov.y += c2*bf2f(src[1]);
        ov.z += c2*bf2f(src[2]); ov.w += c2*bf2f(src[3]);
        *(float4*)op = ov;
    }

    const int lane = t & 63, chl = lane & 15, cs = lane >> 4;
    const int wv = t >> 6, outrow = wv & 1, chhalf = wv >> 1;

    #pragma unroll
    for (int chi = 0; chi < 2; ++chi) {
        const int ch = chhalf*32 + chl + chi*16;
        const float* wch = &wl[ch*26];
        float accp[16];
        #pragma unroll
        for (int p = 0; p < 16; ++p) accp[p] = 0.f;
        #pragma unroll
        for (int kh = 0; kh < 5; ++kh) {
            const u16* src = &lin[((outrow + kh)*64 + ch)*70 + cs*16];
            float rb[20];
            #pragma unroll
            for (int k = 0; k < 10; ++k) {
                u32 u = *(const u32*)(src + 2*k);
                rb[2*k]   = __uint_as_float(u << 16);
                rb[2*k+1] = __uint_as_float(u & 0xFFFF0000u);
            }
            #pragma unroll
            for (int kw = 0; kw < 5; ++kw) {
                float wvv = wch[kh*5 + kw];
                #pragma unroll
                for (int p = 0; p < 16; ++p) accp[p] += rb[p+kw]*wvv;
            }
        }
        float s = gg[ch] * rsqrtf(vv[ch] + 1e-5f);
        float tt = bb[ch] - mm[ch]*s;
        float* op = out + ((size_t)(b*C_ + CS + ch))*HW + (size_t)(orow0+outrow)*64 + cs*16;
        #pragma unroll
        for (int q = 0; q < 4; ++q) {
            float4 ov = *(float4*)(op + q*4);
            ov.x += c2*silu_f(accp[q*4+0]*s + tt);
            ov.y += c2*silu_f(accp[q*4+1]*s + tt);
            ov.z += c2*silu_f(accp[q*4+2]*s + tt);
            ov.w += c2*silu_f(accp[q*4+3]*s + tt);
            *(float4*)(op + q*4) = ov;
        }
    }
}

extern "C" void kernel_launch(void* const* d_in, const int* in_sizes, int n_in,
                              void* d_out, int out_size, void* d_ws, size_t ws_size,
                              hipStream_t stream) {
    const float* x    = (const float*)d_in[0];
    const float* wts  = (const float*)d_in[1];
    const int*   idxs = (const int*)  d_in[2];
    const float* e0w  = (const float*)d_in[3];
    const float* e0g  = (const float*)d_in[4];
    const float* e0b  = (const float*)d_in[5];
    const float* e0m  = (const float*)d_in[6];
    const float* e0v  = (const float*)d_in[7];
    const float* e1dw = (const float*)d_in[8];
    const float* e1pw = (const float*)d_in[9];
    const float* e1g  = (const float*)d_in[10];
    const float* e1b  = (const float*)d_in[11];
    const float* e1m  = (const float*)d_in[12];
    const float* e1v  = (const float*)d_in[13];
    const float* e2aw = (const float*)d_in[14];
    const float* e2ag = (const float*)d_in[15];
    const float* e2ab = (const float*)d_in[16];
    const float* e2am = (const float*)d_in[17];
    const float* e2av = (const float*)d_in[18];
    const float* e2bw = (const float*)d_in[19];
    const float* e2bg = (const float*)d_in[20];
    const float* e2bb = (const float*)d_in[21];
    const float* e2bm = (const float*)d_in[22];
    const float* e2bv = (const float*)d_in[23];

    float* out = (float*)d_out;

    u16* xh   = (u16*)d_ws;                      // [b][66][66][128] bf16, 35.7 MB
    u16* g1   = xh + (size_t)32*66*66*128;       // [b][64][HW] bf16, 16.8 MB
    u16* Wt0f = g1 + (size_t)8388608;            // 73728
    u16* Wt2f = Wt0f + 73728;                    // 73728
    u16* Wt1f = Wt2f + 73728;                    // 8192

    k_prep<<<128, 256, 0, stream>>>(e0w, e2aw, e1pw, Wt0f, Wt2f, Wt1f);
    k_to_nhwc<<<2048, 256, 0, stream>>>(x, wts, idxs, xh);
    k_conv<<<6144, 64, 0, stream>>>(
        xh, x, wts, idxs, Wt0f, Wt2f,
        e0g, e0b, e0m, e0v, e2ag, e2ab, e2am, e2av, out, g1);
    k_e1<<<1024, 256, 0, stream>>>(
        x, wts, idxs, e1dw, Wt1f, e1g, e1b, e1m, e1v, out);
    k_e2b<<<1024, 256, 0, stream>>>(
        g1, wts, idxs, e2bw, e2bg, e2bb, e2bm, e2bv, out);
}

// Round 8
// 116.033 us; speedup vs baseline: 1.7460x; 1.7460x over previous
//
#include <hip/hip_runtime.h>

#define B_  32
#define C_  128
#define CS  64
#define H_  64
#define W_  64
#define HW  (H_*W_)

typedef __attribute__((ext_vector_type(8))) short bf16x8_t;
typedef __attribute__((ext_vector_type(4))) float f32x4_t;
typedef unsigned short u16;
typedef unsigned int   u32;

__device__ __forceinline__ float silu_f(float v) { return v / (1.f + __expf(-v)); }

__device__ __forceinline__ u16 f2bf(float f) {
    u32 u = __float_as_uint(f);
    u = (u + 0x7FFFu + ((u >> 16) & 1u)) >> 16;   // RNE
    return (u16)u;
}
__device__ __forceinline__ float bf2f(u16 u) {
    return __uint_as_float(((u32)u) << 16);
}
__device__ __forceinline__ u32 pack2(float a, float b) {
    return (u32)f2bf(a) | ((u32)f2bf(b) << 16);
}

__device__ __forceinline__ void get_coeffs(const float* __restrict__ wts,
                                           const int* __restrict__ idxs, int b,
                                           float& c0, float& c1, float& c2, float& cid) {
    int   i0 = idxs[b*2+0], i1 = idxs[b*2+1];
    float w0 = wts[b*2+0],  w1 = wts[b*2+1];
    c0  = (i0==0?w0:0.f)   + (i1==0?w1:0.f);
    c1  = (i0==1?w0:0.f)   + (i1==1?w1:0.f);
    c2  = (i0==2?w0:0.f)   + (i1==2?w1:0.f);
    cid = (i0==3?0.1f:0.f) + (i1==3?0.1f:0.f);
}

// ---- weight prep: MFMA-fragment-ordered bf16 weights --------------------------
// Wt0f: e0  [tap9][kc2][cog8][lane64][8]   A[row=co=cog*16+(l&15)][k=kc*32+(l>>4)*8+j]
// Wt2f: e2a [tap9][kc4][cog4][lane64][8]
// Wt1f: e1pw[kc2][cog8][lane64][8]
__global__ __launch_bounds__(256) void k_prep(
    const float* __restrict__ e0w, const float* __restrict__ e2aw, const float* __restrict__ e1pw,
    u16* __restrict__ Wt0f, u16* __restrict__ Wt2f, u16* __restrict__ Wt1f)
{
    const int i0 = blockIdx.x*256 + threadIdx.x, stride = gridDim.x*256;
    for (int i = i0; i < 73728; i += stride) {
        int j = i&7, lane = (i>>3)&63, cog = (i>>9)&7, kc = (i>>12)&1, tap = i>>13;
        int co = cog*16 + (lane&15), ci = kc*32 + (lane>>4)*8 + j;
        Wt0f[i] = f2bf(e0w[(size_t)(co*64 + ci)*9 + tap]);
    }
    for (int i = i0; i < 73728; i += stride) {
        int j = i&7, lane = (i>>3)&63, cog = (i>>9)&3, kc = (i>>11)&3, tap = i>>13;
        int co = cog*16 + (lane&15), ci = kc*32 + (lane>>4)*8 + j;
        Wt2f[i] = f2bf(e2aw[(size_t)(co*128 + ci)*9 + tap]);
    }
    for (int i = i0; i < 8192; i += stride) {
        int j = i&7, lane = (i>>3)&63, cog = (i>>9)&7, kc = (i>>12)&1;
        int co = cog*16 + (lane&15), ci = kc*32 + (lane>>4)*8 + j;
        Wt1f[i] = f2bf(e1pw[(size_t)co*64 + ci]);
    }
}

// ---- NCHW fp32 -> two padded NHWC bf16 planes [b][66][66][64], zero borders ----
__global__ __launch_bounds__(256) void k_to_nhwc(
    const float* __restrict__ x, const float* __restrict__ wts, const int* __restrict__ idxs,
    u16* __restrict__ xhA, u16* __restrict__ xhB)
{
    const int b = blockIdx.y, h = blockIdx.x, t = threadIdx.x;
    float c0, c1, c2, cid;
    get_coeffs(wts, idxs, b, c0, c1, c2, cid);
    if (c0 == 0.f && c2 == 0.f) return;
    const int np = (c2 != 0.f) ? 2 : 1;
    const int chmax = np*64;

    __shared__ float ld[128*66];
    for (int i = t; i < chmax*16; i += 256) {
        int ch = i >> 4, q = i & 15;
        float4 v = *(const float4*)(x + ((size_t)(b*C_+ch))*HW + h*64 + q*4);
        float* p = &ld[ch*66 + q*4];
        p[0] = v.x; p[1] = v.y; p[2] = v.z; p[3] = v.w;
    }
    __syncthreads();

    const int px = t >> 2, sub = t & 3;
    const size_t base64 = ((size_t)(b*66 + h+1)*66 + (px+1))*64;
    for (int c = sub; c < chmax/8; c += 4) {
        uint4 v;
        u32 w[4];
        #pragma unroll
        for (int k = 0; k < 4; ++k)
            w[k] = pack2(ld[(c*8 + 2*k)*66 + px], ld[(c*8 + 2*k + 1)*66 + px]);
        v.x = w[0]; v.y = w[1]; v.z = w[2]; v.w = w[3];
        u16* dst = (c < 8) ? (xhA + base64 + c*8) : (xhB + base64 + (c-8)*8);
        *(uint4*)dst = v;
    }
    // zero border cols 0 and 65 of this row
    for (int i = t; i < 16*np; i += 256) {
        int pl = i >> 4, j = i & 15;
        int col = (j >> 3)*65, cg = j & 7;
        u16* ph = pl ? xhB : xhA;
        uint4 z; z.x = z.y = z.z = z.w = 0u;
        *(uint4*)(ph + ((size_t)(b*66 + h+1)*66 + col)*64 + cg*8) = z;
    }
    // zero border rows 0 / 65
    if (h == 0 || h == 63) {
        int r = (h == 0) ? 0 : 65;
        for (int i = t; i < 66*8*np; i += 256) {
            int pl = i / (66*8), j = i % (66*8);
            int col = j >> 3, cg = j & 7;
            u16* ph = pl ? xhB : xhA;
            uint4 z; z.x = z.y = z.z = z.w = 0u;
            *(uint4*)(ph + ((size_t)(b*66 + r)*64*66/64*64 + (size_t)col*64) + cg*8) = z;
        }
    }
}

// ---- conv3x3 body: LDS-staged B (XOR-swizzled), A depth-1 prefetch, MFMA ------
// MODE 0: e0  (CIN=64,  1 plane, COUT=128): out = cexp*silu(bn(conv)) + cid*x
// MODE 1: e2a (CIN=128, 2 planes, COUT=64): g1 = silu(bn(conv)) bf16
template<int MODE>
__device__ __forceinline__ void conv_body(
    u16* lin, const u16* __restrict__ xhA, const u16* __restrict__ xhB,
    const float* __restrict__ x, const u16* __restrict__ Wtf,
    const float* __restrict__ gg, const float* __restrict__ bbn,
    const float* __restrict__ mm, const float* __restrict__ vv,
    float* __restrict__ out, u16* __restrict__ g1,
    int b, int orow0, int t, float cexp, float cid)
{
    constexpr int NPL  = (MODE == 0) ? 1 : 2;
    constexpr int NCF  = (MODE == 0) ? 4 : 2;
    constexpr int COUT = (MODE == 0) ? 128 : 64;
    constexpr int KCT  = (MODE == 0) ? 2 : 4;
    constexpr int NIT  = 9*KCT;

    // stage 4 padded rows (orow0..orow0+3) x 66 cols x 64ch per plane, 33792 B,
    // linear LDS dest, inverse-XOR-swizzled source (T2 both-sides rule)
    const size_t src0 = ((size_t)(b*66 + orow0))*66*64;
    #pragma unroll
    for (int pl = 0; pl < NPL; ++pl) {
        const u16* sp = (pl ? xhB : xhA) + src0;
        char* lp = ((char*)lin) + pl*33792;
        for (int d = t*16; d < 33792; d += 4096) {
            u32 s = (u32)d ^ ((((u32)d >> 7) & 7u) << 4);
            *(uint4*)(lp + d) = *(const uint4*)((const char*)sp + s);
        }
    }
    __syncthreads();

    const int lane = t & 63, l15 = lane & 15, kg = lane >> 4;
    const int wv = t >> 6, cw = wv >> 1, rw = wv & 1;
    const int cobase = cw * (NCF*16);
    const int row = orow0 + rw;

    f32x4_t acc[NCF][4];
    #pragma unroll
    for (int cf = 0; cf < NCF; ++cf)
        #pragma unroll
        for (int pf = 0; pf < 4; ++pf)
            acc[cf][pf] = (f32x4_t){0.f, 0.f, 0.f, 0.f};

    const u16* wb = Wtf + (size_t)(cobase >> 4)*512 + (size_t)lane*8;

    bf16x8_t aC[NCF], aN[NCF];
    auto loadA = [&](int it, bf16x8_t* a) {
        const u16* wt = wb + (size_t)(it*(COUT/16))*512;
        #pragma unroll
        for (int cf = 0; cf < NCF; ++cf)
            a[cf] = *(const bf16x8_t*)(wt + (cf << 9));
    };
    auto ldsB = [&](int it, int pf) -> bf16x8_t {
        const int tap = it / KCT, kcg = it % KCT;
        const int pl = (MODE == 0) ? 0 : (kcg >> 1);
        const int kc = (MODE == 0) ? kcg : (kcg & 1);
        const int dh = tap / 3, dwp = tap % 3;
        const int p  = (rw + dh)*66 + pf*16 + l15 + dwp;
        u32 a = (u32)p*128 + (u32)kc*64 + (u32)kg*16;
        a ^= ((u32)(p & 7)) << 4;
        return *(const bf16x8_t*)(((const char*)lin) + pl*33792 + a);
    };

    loadA(0, aC);
    #pragma unroll
    for (int it = 0; it < NIT; ++it) {
        bf16x8_t* ac = (it & 1) ? aN : aC;
        bf16x8_t* an = (it & 1) ? aC : aN;
        if (it + 1 < NIT) loadA(it + 1, an);
        bf16x8_t bfr[4];
        #pragma unroll
        for (int pf = 0; pf < 4; ++pf) bfr[pf] = ldsB(it, pf);
        #pragma unroll
        for (int pf = 0; pf < 4; ++pf)
            #pragma unroll
            for (int cf = 0; cf < NCF; ++cf)
                acc[cf][pf] = __builtin_amdgcn_mfma_f32_16x16x32_bf16(ac[cf], bfr[pf], acc[cf][pf], 0, 0, 0);
    }

    // D: col=lane&15=pixel, row=(lane>>4)*4+reg=cout
    #pragma unroll
    for (int cf = 0; cf < NCF; ++cf) {
        float sarr[4], tarr[4];
        #pragma unroll
        for (int r = 0; r < 4; ++r) {
            int co = cobase + cf*16 + kg*4 + r;
            float s = gg[co] * rsqrtf(vv[co] + 1e-5f);
            sarr[r] = s; tarr[r] = bbn[co] - mm[co]*s;
        }
        #pragma unroll
        for (int pf = 0; pf < 4; ++pf) {
            int px = pf*16 + l15;
            size_t rowoff = (size_t)row*64 + px;
            #pragma unroll
            for (int r = 0; r < 4; ++r) {
                int co = cobase + cf*16 + kg*4 + r;
                float v = silu_f(acc[cf][pf][r]*sarr[r] + tarr[r]);
                if (MODE == 0) {
                    size_t o = ((size_t)(b*C_+co))*HW + rowoff;
                    float idv = (cid != 0.f) ? cid*x[o] : 0.f;
                    out[o] = cexp*v + idv;
                } else {
                    g1[((size_t)(b*CS+co))*HW + rowoff] = f2bf(v);
                }
            }
        }
    }
}

// ---- merged conv kernel: 256 thr (4 waves), grid (64, B) ----------------------
// bx<32: e0 band bx (c0==0 -> identity init); bx>=32: e2a band bx-32
__global__ __launch_bounds__(256, 3) void k_conv(
    const u16* __restrict__ xhA, const u16* __restrict__ xhB, const float* __restrict__ x,
    const float* __restrict__ wts, const int* __restrict__ idxs,
    const u16* __restrict__ Wt0f, const u16* __restrict__ Wt2f,
    const float* __restrict__ e0g, const float* __restrict__ e0b,
    const float* __restrict__ e0m, const float* __restrict__ e0v,
    const float* __restrict__ e2ag, const float* __restrict__ e2ab,
    const float* __restrict__ e2am, const float* __restrict__ e2av,
    float* __restrict__ out, u16* __restrict__ g1)
{
    __shared__ u16 lin[2*16896];   // 67.6 KB
    const int b = blockIdx.y, bx = blockIdx.x, t = threadIdx.x;
    float c0, c1, c2, cid;
    get_coeffs(wts, idxs, b, c0, c1, c2, cid);

    if (bx < 32) {
        const int orow0 = bx*2;
        if (c0 == 0.f) {   // identity-only init of these 2 rows (all 128 ch)
            for (int i = t; i < 4096; i += 256) {
                int q = i & 15, r = (i >> 4) & 1, ch = i >> 5;
                size_t o = ((size_t)(b*C_+ch))*HW + (size_t)(orow0+r)*64 + q*4;
                float4 ov;
                if (cid != 0.f) {
                    float4 xv = *(const float4*)(x + o);
                    ov.x = cid*xv.x; ov.y = cid*xv.y; ov.z = cid*xv.z; ov.w = cid*xv.w;
                } else { ov.x = ov.y = ov.z = ov.w = 0.f; }
                *(float4*)(out + o) = ov;
            }
            return;
        }
        conv_body<0>(lin, xhA, xhB, x, Wt0f, e0g, e0b, e0m, e0v, out, nullptr,
                     b, orow0, t, c0, cid);
    } else {
        if (c2 == 0.f) return;
        conv_body<1>(lin, xhA, xhB, x, Wt2f, e2ag, e2ab, e2am, e2av, nullptr, g1,
                     b, (bx-32)*2, t, c2, 0.f);
    }
}

// ---- fused e1: dw5x5(x_ir) in LDS -> pw1x1 MFMA -> BN/SiLU -> out += c1*e1 ----
__global__ __launch_bounds__(256) void k_e1(
    const float* __restrict__ x, const float* __restrict__ wts, const int* __restrict__ idxs,
    const float* __restrict__ dww, const u16* __restrict__ Wt1f,
    const float* __restrict__ gg, const float* __restrict__ bb,
    const float* __restrict__ mm, const float* __restrict__ vv,
    float* __restrict__ out)
{
    const int b = blockIdx.y, band = blockIdx.x, t = threadIdx.x;
    const int orow0 = band*2;

    float c0, c1, c2, cid;
    get_coeffs(wts, idxs, b, c0, c1, c2, cid);
    if (c1 == 0.f) return;

    __shared__ u16  lin[6*64*70];   // [row6][ch64][col70] cols -2..65 (+pad), bf16
    __shared__ u16  lout[128*72];   // [px128][ci72pad] bf16
    __shared__ float wl[64*26];

    for (int i = t; i < 64*25; i += 256) wl[(i/25)*26 + (i%25)] = dww[i];
    for (int i = t; i < 6*64*16; i += 256) {
        int q = i & 15, ch = (i >> 4) & 63, r = i >> 10;
        int hh = orow0 - 2 + r;
        u32 w0 = 0u, w1 = 0u;
        if (hh >= 0 && hh < H_) {
            float4 v = *(const float4*)(x + ((size_t)(b*C_ + CS + ch))*HW + hh*64 + q*4);
            w0 = pack2(v.x, v.y); w1 = pack2(v.z, v.w);
        }
        u32* dst = (u32*)&lin[(r*64 + ch)*70 + 2 + q*4];
        dst[0] = w0; dst[1] = w1;
    }
    for (int i = t; i < 6*64; i += 256) {
        int ch = i & 63, r = i >> 6;
        *(u32*)&lin[(r*64 + ch)*70]      = 0u;
        u32* e = (u32*)&lin[(r*64 + ch)*70 + 66];
        e[0] = 0u; e[1] = 0u;
    }
    __syncthreads();

    const int lane = t & 63, chl = lane & 15, cs = lane >> 4;
    const int wv = t >> 6, outrow = wv & 1, chhalf = wv >> 1;

    #pragma unroll
    for (int chi = 0; chi < 2; ++chi) {
        const int ch = chhalf*32 + chl + chi*16;
        const float* wch = &wl[ch*26];
        float accp[16];
        #pragma unroll
        for (int p = 0; p < 16; ++p) accp[p] = 0.f;
        #pragma unroll
        for (int kh = 0; kh < 5; ++kh) {
            const u16* src = &lin[((outrow + kh)*64 + ch)*70 + cs*16];
            float rb[20];
            #pragma unroll
            for (int k = 0; k < 10; ++k) {
                u32 u = *(const u32*)(src + 2*k);
                rb[2*k]   = __uint_as_float(u << 16);
                rb[2*k+1] = __uint_as_float(u & 0xFFFF0000u);
            }
            #pragma unroll
            for (int kw = 0; kw < 5; ++kw) {
                float wvv = wch[kh*5 + kw];
                #pragma unroll
                for (int p = 0; p < 16; ++p) accp[p] += rb[p+kw]*wvv;
            }
        }
        const int px0 = outrow*64 + cs*16;
        #pragma unroll
        for (int p = 0; p < 16; ++p) lout[(px0+p)*72 + ch] = f2bf(accp[p]);
    }
    __syncthreads();

    const int l15 = lane & 15, kg = lane >> 4;
    const int cw = wv >> 1, pwv = wv & 1;
    f32x4_t acc[4][4];
    #pragma unroll
    for (int cf = 0; cf < 4; ++cf)
        #pragma unroll
        for (int pf = 0; pf < 4; ++pf)
            acc[cf][pf] = (f32x4_t){0.f, 0.f, 0.f, 0.f};

    #pragma unroll
    for (int kc = 0; kc < 2; ++kc) {
        const u16* wt = Wt1f + (((size_t)(kc*8 + cw*4)) << 9) + lane*8;
        bf16x8_t af[4];
        #pragma unroll
        for (int cf = 0; cf < 4; ++cf) af[cf] = *(const bf16x8_t*)(wt + (cf << 9));
        const int k0 = kc*32 + kg*8;
        #pragma unroll
        for (int pf = 0; pf < 4; ++pf) {
            bf16x8_t bfr = *(const bf16x8_t*)&lout[(pwv*64 + pf*16 + l15)*72 + k0];
            #pragma unroll
            for (int cf = 0; cf < 4; ++cf)
                acc[cf][pf] = __builtin_amdgcn_mfma_f32_16x16x32_bf16(af[cf], bfr, acc[cf][pf], 0, 0, 0);
        }
    }

    #pragma unroll
    for (int cf = 0; cf < 4; ++cf) {
        float sarr[4], tarr[4];
        #pragma unroll
        for (int r = 0; r < 4; ++r) {
            int co = cw*64 + cf*16 + kg*4 + r;
            float s = gg[co] * rsqrtf(vv[co] + 1e-5f);
            sarr[r] = s; tarr[r] = bb[co] - mm[co]*s;
        }
        #pragma unroll
        for (int pf = 0; pf < 4; ++pf) {
            int px = pwv*64 + pf*16 + l15;
            size_t rowoff = (size_t)(orow0 + (px>>6))*64 + (px&63);
            #pragma unroll
            for (int r = 0; r < 4; ++r) {
                int co = cw*64 + cf*16 + kg*4 + r;
                float v = silu_f(acc[cf][pf][r]*sarr[r] + tarr[r]);
                out[((size_t)(b*C_+co))*HW + rowoff] += c1*v;
            }
        }
    }
}

// ---- e2b: out[:, :64] += c2*g1 ; out[:, 64:] += c2*silu(bn(dw5x5(g1))) --------
__global__ __launch_bounds__(256) void k_e2b(
    const u16* __restrict__ g1, const float* __restrict__ wts, const int* __restrict__ idxs,
    const float* __restrict__ dww, const float* __restrict__ gg, const float* __restrict__ bb,
    const float* __restrict__ mm, const float* __restrict__ vv, float* __restrict__ out)
{
    const int b = blockIdx.y, band = blockIdx.x, t = threadIdx.x;
    const int orow0 = band*2;

    float c0, c1, c2, cid;
    get_coeffs(wts, idxs, b, c0, c1, c2, cid);
    if (c2 == 0.f) return;

    __shared__ u16  lin[6*64*70];
    __shared__ float wl[64*26];

    for (int i = t; i < 64*25; i += 256) wl[(i/25)*26 + (i%25)] = dww[i];
    for (int i = t; i < 6*64*16; i += 256) {
        int q = i & 15, ch = (i >> 4) & 63, r = i >> 10;
        int hh = orow0 - 2 + r;
        u32 w0 = 0u, w1 = 0u;
        if (hh >= 0 && hh < H_) {
            const u32* src = (const u32*)(g1 + ((size_t)(b*CS+ch))*HW + hh*64 + q*4);
            w0 = src[0]; w1 = src[1];
        }
        u32* dst = (u32*)&lin[(r*64 + ch)*70 + 2 + q*4];
        dst[0] = w0; dst[1] = w1;
    }
    for (int i = t; i < 6*64; i += 256) {
        int ch = i & 63, r = i >> 6;
        *(u32*)&lin[(r*64 + ch)*70] = 0u;
        u32* e = (u32*)&lin[(r*64 + ch)*70 + 66];
        e[0] = 0u; e[1] = 0u;
    }
    __syncthreads();

    // out[:, :64] += c2*g1 for the 2 center rows (lin rows 2,3)
    for (int i = t; i < 2*64*16; i += 256) {
        int q = i & 15, ch = (i >> 4) & 63, r = i >> 10;
        const u16* src = &lin[((r+2)*64 + ch)*70 + 2 + q*4];
        float* op = out + ((size_t)(b*C_+ch))*HW + (size_t)(orow0+r)*64 + q*4;
        float4 ov = *(float4*)op;
        ov.x += c2*bf2f(src[0]); ov.y += c2*bf2f(src[1]);
        ov.z += c2*bf2f(src[2]); ov.w += c2*bf2f(src[3]);
        *(float4*)op = ov;
    }

    const int lane = t & 63, chl = lane & 15, cs = lane >> 4;
    const int wv = t >> 6, outrow = wv & 1, chhalf = wv >> 1;

    #pragma unroll
    for (int chi = 0; chi < 2; ++chi) {
        const int ch = chhalf*32 + chl + chi*16;
        const float* wch = &wl[ch*26];
        float accp[16];
        #pragma unroll
        for (int p = 0; p < 16; ++p) accp[p] = 0.f;
        #pragma unroll
        for (int kh = 0; kh < 5; ++kh) {
            const u16* src = &lin[((outrow + kh)*64 + ch)*70 + cs*16];
            float rb[20];
            #pragma unroll
            for (int k = 0; k < 10; ++k) {
                u32 u = *(const u32*)(src + 2*k);
                rb[2*k]   = __uint_as_float(u << 16);
                rb[2*k+1] = __uint_as_float(u & 0xFFFF0000u);
            }
            #pragma unroll
            for (int kw = 0; kw < 5; ++kw) {
                float wvv = wch[kh*5 + kw];
                #pragma unroll
                for (int p = 0; p < 16; ++p) accp[p] += rb[p+kw]*wvv;
            }
        }
        float s = gg[ch] * rsqrtf(vv[ch] + 1e-5f);
        float tt = bb[ch] - mm[ch]*s;
        float* op = out + ((size_t)(b*C_ + CS + ch))*HW + (size_t)(orow0+outrow)*64 + cs*16;
        #pragma unroll
        for (int q = 0; q < 4; ++q) {
            float4 ov = *(float4*)(op + q*4);
            ov.x += c2*silu_f(accp[q*4+0]*s + tt);
            ov.y += c2*silu_f(accp[q*4+1]*s + tt);
            ov.z += c2*silu_f(accp[q*4+2]*s + tt);
            ov.w += c2*silu_f(accp[q*4+3]*s + tt);
            *(float4*)(op + q*4) = ov;
        }
    }
}

extern "C" void kernel_launch(void* const* d_in, const int* in_sizes, int n_in,
                              void* d_out, int out_size, void* d_ws, size_t ws_size,
                              hipStream_t stream) {
    const float* x    = (const float*)d_in[0];
    const float* wts  = (const float*)d_in[1];
    const int*   idxs = (const int*)  d_in[2];
    const float* e0w  = (const float*)d_in[3];
    const float* e0g  = (const float*)d_in[4];
    const float* e0b  = (const float*)d_in[5];
    const float* e0m  = (const float*)d_in[6];
    const float* e0v  = (const float*)d_in[7];
    const float* e1dw = (const float*)d_in[8];
    const float* e1pw = (const float*)d_in[9];
    const float* e1g  = (const float*)d_in[10];
    const float* e1b  = (const float*)d_in[11];
    const float* e1m  = (const float*)d_in[12];
    const float* e1v  = (const float*)d_in[13];
    const float* e2aw = (const float*)d_in[14];
    const float* e2ag = (const float*)d_in[15];
    const float* e2ab = (const float*)d_in[16];
    const float* e2am = (const float*)d_in[17];
    const float* e2av = (const float*)d_in[18];
    const float* e2bw = (const float*)d_in[19];
    const float* e2bg = (const float*)d_in[20];
    const float* e2bb = (const float*)d_in[21];
    const float* e2bm = (const float*)d_in[22];
    const float* e2bv = (const float*)d_in[23];

    float* out = (float*)d_out;

    const size_t PLANE = (size_t)32*66*66*64;    // u16 per plane (17.8 MB)
    u16* xhA  = (u16*)d_ws;
    u16* xhB  = xhA + PLANE;
    u16* g1   = xhB + PLANE;                     // 16.8 MB
    u16* Wt0f = g1 + (size_t)8388608;
    u16* Wt2f = Wt0f + 73728;
    u16* Wt1f = Wt2f + 73728;

    k_prep<<<128, 256, 0, stream>>>(e0w, e2aw, e1pw, Wt0f, Wt2f, Wt1f);
    k_to_nhwc<<<dim3(64, B_), 256, 0, stream>>>(x, wts, idxs, xhA, xhB);
    k_conv<<<dim3(64, B_), 256, 0, stream>>>(
        xhA, xhB, x, wts, idxs, Wt0f, Wt2f,
        e0g, e0b, e0m, e0v, e2ag, e2ab, e2am, e2av, out, g1);
    k_e1<<<dim3(32, B_), 256, 0, stream>>>(
        x, wts, idxs, e1dw, Wt1f, e1g, e1b, e1m, e1v, out);
    k_e2b<<<dim3(32, B_), 256, 0, stream>>>(
        g1, wts, idxs, e2bw, e2bg, e2bb, e2bm, e2bv, out);
}